// Round 2
// baseline (500.366 us; speedup 1.0000x reference)
//
#include <hip/hip_runtime.h>
#include <math.h>

#define TOKENS 16384
#define DIM    4096
#define NEXP   64
#define KSPLIT 8
#define KPW    (DIM / KSPLIT)      // 512 k per wave
#define NF4    (KPW / 4)           // 128 float4 iterations per wave

// ---- pre-pass: W[64][4096] -> Wt[4096][64] (1 MB, trivial) ----
__global__ __launch_bounds__(256)
void transpose_w(const float* __restrict__ W, float* __restrict__ Wt)
{
    const int idx = blockIdx.x * 256 + threadIdx.x;   // 262144 elements
    const int e = idx & (NEXP - 1);
    const int k = idx >> 6;
    // consecutive threads: same k, consecutive e -> coalesced Wt writes
    Wt[(size_t)k * NEXP + e] = W[(size_t)e * DIM + k];
}

// ---- main: rank-1 SGPR-broadcast gating GEMV + fused softmax/top-2 ----
__global__ __launch_bounds__(512, 1)
void gating_kernel(const float* __restrict__ x,
                   const float* __restrict__ Wt,
                   const float* __restrict__ bias,
                   float* __restrict__ out)
{
    __shared__ float red[4][64][NEXP];   // 64 KB reduction scratch

    const int tid  = threadIdx.x;
    const int lane = tid & 63;
    const int wid  = __builtin_amdgcn_readfirstlane(tid >> 6);  // provably uniform
    const int tok  = blockIdx.x * 64 + lane;

    float acc[64];
    if (wid == 0) {
        // fold bias into wave 0's partial (one wave only: partials are summed)
#pragma unroll
        for (int c = 0; c < 16; ++c) {
            const float4 bv = *(const float4*)(bias + c * 4);
            acc[c*4+0] = bv.x; acc[c*4+1] = bv.y; acc[c*4+2] = bv.z; acc[c*4+3] = bv.w;
        }
    } else {
#pragma unroll
        for (int e = 0; e < 64; ++e) acc[e] = 0.f;
    }

    // x: per-lane streaming of this token's K-slice (read exactly once, no LDS)
    const float4* xr = (const float4*)(x + (size_t)tok * DIM + wid * KPW);
    // Wt: wave-uniform address -> s_load into SGPRs, broadcast into v_fmac
    const float* wb = Wt + (size_t)(wid * KPW) * NEXP;

    float4 xv = xr[0];
    for (int i = 0; i < NF4; ++i) {
        float4 xn = xv;
        if (i + 1 < NF4) xn = xr[i + 1];          // prefetch next x quad
        const float* wr = wb + (size_t)i * (4 * NEXP);
#pragma unroll
        for (int kk = 0; kk < 4; ++kk) {
            const float xk = (kk == 0) ? xv.x : (kk == 1) ? xv.y
                           : (kk == 2) ? xv.z : xv.w;
            const float* wkr = wr + kk * NEXP;    // uniform: Wt row for this k
#pragma unroll
            for (int e4 = 0; e4 < 16; ++e4) {
                const float4 w = *(const float4*)(wkr + e4 * 4);
                acc[e4*4+0] = fmaf(xk, w.x, acc[e4*4+0]);
                acc[e4*4+1] = fmaf(xk, w.y, acc[e4*4+1]);
                acc[e4*4+2] = fmaf(xk, w.z, acc[e4*4+2]);
                acc[e4*4+3] = fmaf(xk, w.w, acc[e4*4+3]);
            }
        }
        xv = xn;
    }

    // ---- cross-wave K reduction: 3-round LDS tree, float4, XOR-swizzled ----
    // swizzle chunk index by (lane&7): row stride 256B => unswizzled all lanes
    // hit one bank-quad; XOR spreads over 8 quads (bandwidth floor only).
    auto lds_write = [&](int slot) {
#pragma unroll
        for (int c = 0; c < 16; ++c) {
            const int cs = c ^ (lane & 7);
            *(float4*)&red[slot][lane][cs * 4] =
                make_float4(acc[c*4], acc[c*4+1], acc[c*4+2], acc[c*4+3]);
        }
    };
    auto lds_add = [&](int slot) {
#pragma unroll
        for (int c = 0; c < 16; ++c) {
            const int cs = c ^ (lane & 7);
            const float4 v = *(const float4*)&red[slot][lane][cs * 4];
            acc[c*4+0] += v.x; acc[c*4+1] += v.y;
            acc[c*4+2] += v.z; acc[c*4+3] += v.w;
        }
    };

    if (wid >= 4) lds_write(wid - 4);
    __syncthreads();
    if (wid < 4) lds_add(wid);
    __syncthreads();
    if (wid == 2 || wid == 3) lds_write(wid - 2);
    __syncthreads();
    if (wid < 2) lds_add(wid);
    __syncthreads();
    if (wid == 1) lds_write(0);
    __syncthreads();

    if (wid == 0) {
        lds_add(0);
        // each lane now holds all 64 scores for its token, in registers.
        // top-2 scan, fully unrolled (compile-time indices -> no scratch).
        float m1 = -INFINITY, m2 = -INFINITY;
        int i1 = 0, i2 = 0;
#pragma unroll
        for (int e = 0; e < 64; ++e) {
            const float v = acc[e];
            const bool gt1 = v > m1;          // strict: ties keep lowest index
            const bool gt2 = v > m2;
            m2 = gt1 ? m1 : (gt2 ? v : m2);
            i2 = gt1 ? i1 : (gt2 ? e : i2);
            m1 = gt1 ? v : m1;
            i1 = gt1 ? e : i1;
        }
        float denom = 0.f;
#pragma unroll
        for (int e = 0; e < 64; ++e) denom += __expf(acc[e] - m1);
        const float inv = 1.0f / denom;       // prob of argmax
        // output: [indices (16384x2) as float][values (16384x2)]
        out[2*tok + 0] = (float)i1;
        out[2*tok + 1] = (float)i2;
        out[2*TOKENS + 2*tok + 0] = inv;
        out[2*TOKENS + 2*tok + 1] = __expf(m2 - m1) * inv;
    }
}

extern "C" void kernel_launch(void* const* d_in, const int* in_sizes, int n_in,
                              void* d_out, int out_size, void* d_ws, size_t ws_size,
                              hipStream_t stream)
{
    const float* x = (const float*)d_in[0];   // [16384, 4096] fp32
    const float* W = (const float*)d_in[1];   // [64, 4096] fp32
    const float* b = (const float*)d_in[2];   // [64] fp32
    float* out = (float*)d_out;               // [2*16384*2] fp32: indices, values
    float* Wt  = (float*)d_ws;                // 4096*64*4 = 1 MB scratch

    transpose_w<<<dim3((DIM * NEXP) / 256), dim3(256), 0, stream>>>(W, Wt);
    gating_kernel<<<dim3(TOKENS / 64), dim3(512), 0, stream>>>(x, Wt, b, (float*)d_out);
}